// Round 2
// baseline (297.740 us; speedup 1.0000x reference)
//
#include <hip/hip_runtime.h>
#include <math.h>

// Problem constants (from reference):
//   B=64, T=512, D=1024, VOCAB=50257
// Outputs: y[B,D] then y_hat[B,D], concatenated fp32 in d_out.
constexpr int B = 64;
constexpr int T = 512;
constexpr int D = 1024;
constexpr int NT = 16;            // t-chunks per batch row
constexpr int CHUNK = T / NT;     // 32 rows per block
constexpr size_t PART_ELEMS = (size_t)NT * B * 2 * D;   // 2M floats = 8 MB

typedef float f32x4 __attribute__((ext_vector_type(4)));  // clang-native vec:
// __builtin_nontemporal_load requires scalar/native-vector pointee (NOT
// HIP_vector_type float4 — that fails to compile on gfx950).

// d_ws layout:
//   part[NT][B][2*D] fp32 (8 MB)  — per-chunk partials (s then y_hat)
//   cnt[B] int                    — arrival tickets (zeroed by k0_init each iter)
//
// Fused design: each active (b,tc) block computes its partial, releases it
// (threadfence), takes a ticket; the LAST arriver for b sums the slots in
// ascending tc order (bit-identical to the old k2) and writes y / y_hat.
// Finalization overlaps with other b's still-running partial blocks, and the
// second heavyweight dispatch disappears.

__global__ __launch_bounds__(64) void k0_init(int* __restrict__ cnt) {
    cnt[threadIdx.x] = 0;          // 64 threads, 1 block
}

__global__ __launch_bounds__(256) void k_fused(
    const float* __restrict__ vs,      // [B,T,D]
    const int*   __restrict__ slen,    // [B]
    const int*   __restrict__ words,   // [B,T]
    const float* __restrict__ wts,     // [VOCAB]
    float*       __restrict__ part,    // [NT][B][2*D] workspace
    int*         __restrict__ cnt,     // [B] tickets
    float*       __restrict__ out)     // [2,B,D]
{
    const int bid = blockIdx.x;
    const int b   = bid & (B - 1);     // spread b across consecutive blocks
    const int tc  = bid >> 6;
    const int len = slen[b];
    const int nact = (len + CHUNK - 1) / CHUNK;   // active chunks, >= 1
    if (tc >= nact) return;            // whole chunk masked; slot never read

    const int t0 = tc * CHUNK;
    const int t1 = (t0 + CHUNK < len) ? (t0 + CHUNK) : len;

    __shared__ float wbuf[CHUNK];
    __shared__ int   ticket;
    const int tid = threadIdx.x;
    if (tid < CHUNK) {
        const int t = t0 + tid;
        wbuf[tid] = (t < len) ? wts[words[b * T + t]] : 0.0f;
    }
    __syncthreads();

    // ---- partial accumulation over this chunk's rows (identical math/order
    //      to the previous k1) ----
    const int d0 = tid * 4;
    const f32x4* vp = (const f32x4*)(vs + ((size_t)(b * T + t0)) * D + d0);
    f32x4 s  = {0.f, 0.f, 0.f, 0.f};
    f32x4 yh = {0.f, 0.f, 0.f, 0.f};

    #pragma unroll 4
    for (int t = t0; t < t1; ++t) {
        const f32x4 v = __builtin_nontemporal_load(vp);  // stream-once: don't evict partials from L2
        vp += D / 4;                   // next row
        const float w = wbuf[t - t0];  // block-uniform -> LDS broadcast
        s  += v;
        yh += v * w;
    }

    float* p = part + ((size_t)tc * B + b) * (2 * D) + d0;
    *(f32x4*)p       = s;
    *(f32x4*)(p + D) = yh;

    // ---- release partials, take ticket ----
    __threadfence();                   // agent-scope release: every wave drains
    __syncthreads();                   //   + all waves' fences done before ticket
    if (tid == 0) ticket = atomicAdd(&cnt[b], 1);
    __syncthreads();
    if (ticket != nact - 1) return;    // not the last arriver for this b

    // ---- last block for b: finalize (was k2) ----
    __threadfence();                   // acquire: invalidate before reading peers

    f32x4 S  = {0.f, 0.f, 0.f, 0.f};
    f32x4 YH = {0.f, 0.f, 0.f, 0.f};
    for (int c = 0; c < nact; ++c) {   // ascending order == old k2 (determinism)
        const float* q = part + ((size_t)c * B + b) * (2 * D) + d0;
        const f32x4 ps = *(const f32x4*)q;
        const f32x4 py = *(const f32x4*)(q + D);
        S  += ps;
        YH += py;
    }

    float a = fabsf(S.x) + fabsf(S.y) + fabsf(S.z) + fabsf(S.w);
    for (int off = 32; off > 0; off >>= 1)
        a += __shfl_down(a, off, 64);

    __shared__ float psum[4];
    const int wave = tid >> 6;
    const int lane = tid & 63;
    if (lane == 0) psum[wave] = a;
    __syncthreads();
    const float tot = psum[0] + psum[1] + psum[2] + psum[3];
    const float inv = 1.0f / sqrtf(tot);

    f32x4 y = S * inv;
    *(f32x4*)(out + (size_t)b * D + d0)       = y;   // y
    *(f32x4*)(out + (size_t)(B + b) * D + d0) = YH;  // y_hat
}

extern "C" void kernel_launch(void* const* d_in, const int* in_sizes, int n_in,
                              void* d_out, int out_size, void* d_ws, size_t ws_size,
                              hipStream_t stream) {
    const float* vs    = (const float*)d_in[0];   // [B,T,D] fp32
    const int*   slen  = (const int*)  d_in[1];   // [B]
    const int*   words = (const int*)  d_in[2];   // [B,T]
    const float* wts   = (const float*)d_in[3];   // [VOCAB]
    float* out  = (float*)d_out;                  // [2*B*D] fp32
    float* part = (float*)d_ws;                   // 8 MB partials
    int*   cnt  = (int*)(part + PART_ELEMS);      // [B] tickets after partials

    k0_init<<<1,      64,  0, stream>>>(cnt);
    k_fused<<<B * NT, 256, 0, stream>>>(vs, slen, words, wts, part, cnt, out);
}

// Round 3
// 187.730 us; speedup vs baseline: 1.5860x; 1.5860x over previous
//
#include <hip/hip_runtime.h>
#include <math.h>

// Problem constants (from reference):
//   B=64, T=512, D=1024, VOCAB=50257
// Outputs: y[B,D] then y_hat[B,D], concatenated fp32 in d_out.
constexpr int B = 64;
constexpr int T = 512;
constexpr int D = 1024;
constexpr int NT = 16;            // t-chunks per batch row
constexpr int CHUNK = T / NT;     // 32 rows per block

// d_ws layout: partials[B][NT][2*D] fp32 = 8 MB.
//   part[b][tc][0:D]   = sum over chunk tc of vs rows      (s partial)
//   part[b][tc][D:2D]  = sum over chunk tc of vs*w rows    (y_hat partial)
// [b][tc] layout (vs R0's [tc][b]) makes k2's per-b reads one contiguous
// ~nact*8KB streak — better L2 locality for the finalize pass.
// Chunks with tc*CHUNK >= len[b] are never written; k2 computes the active
// chunk count from len[b] and never reads the poisoned regions.
//
// NOTE (R2 post-mortem): do NOT fuse these with last-block-arrival +
// __threadfence(). Device-scope fences on gfx950 = per-block L2
// writeback/invalidate (XCDs non-coherent) -> 141 us stall vs ~28 us for
// the two-kernel version. Kernel boundary IS the cheap device-wide release.
// Also: no nontemporal loads — the 128 MB input is L3-resident across
// iterations (FETCH 30 MB << 67 MB read); NT policy would evict it.

__global__ __launch_bounds__(256) void k1_partial(
    const float* __restrict__ vs,      // [B,T,D]
    const int*   __restrict__ slen,    // [B]
    const int*   __restrict__ words,   // [B,T]
    const float* __restrict__ wts,     // [VOCAB]
    float*       __restrict__ part)    // [B][NT][2*D] workspace
{
    const int bid = blockIdx.x;
    const int b  = bid & (B - 1);      // spread b across consecutive blocks
    const int tc = bid >> 6;
    const int len = slen[b];
    const int t0 = tc * CHUNK;
    if (t0 >= len) return;             // whole chunk masked out; never read by k2
    const int t1 = (t0 + CHUNK < len) ? (t0 + CHUNK) : len;

    __shared__ float wbuf[CHUNK];
    const int tid = threadIdx.x;
    if (tid < CHUNK) {
        const int t = t0 + tid;
        wbuf[tid] = (t < len) ? wts[words[b * T + t]] : 0.0f;
    }
    __syncthreads();

    const int d0 = tid * 4;
    const float4* vp = (const float4*)(vs + ((size_t)(b * T + t0)) * D + d0);
    float4 s  = make_float4(0.f, 0.f, 0.f, 0.f);
    float4 yh = make_float4(0.f, 0.f, 0.f, 0.f);

    #pragma unroll 4
    for (int t = t0; t < t1; ++t) {
        const float4 v = *vp;
        vp += D / 4;                   // next row
        const float w = wbuf[t - t0];  // block-uniform -> LDS broadcast
        s.x += v.x; s.y += v.y; s.z += v.z; s.w += v.w;
        yh.x += v.x * w; yh.y += v.y * w; yh.z += v.z * w; yh.w += v.w * w;
    }

    float* p = part + ((size_t)b * NT + tc) * (2 * D) + d0;
    *(float4*)p       = s;
    *(float4*)(p + D) = yh;
}

// K2: one block per b. Sum active partials (ascending tc — same order every
// run, deterministic), reduce sum|s| across the block, write y and y_hat.
__global__ __launch_bounds__(256) void k2_finalize(
    const float* __restrict__ part,    // [B][NT][2*D]
    const int*   __restrict__ slen,    // [B]
    float*       __restrict__ out)     // [2,B,D]
{
    const int b = blockIdx.x;
    const int tid = threadIdx.x;
    const int len = slen[b];
    const int nact = (len + CHUNK - 1) / CHUNK;   // active chunks, >= 1

    const int d0 = tid * 4;
    float4 s  = make_float4(0.f, 0.f, 0.f, 0.f);
    float4 yh = make_float4(0.f, 0.f, 0.f, 0.f);
    for (int tc = 0; tc < nact; ++tc) {
        const float* p = part + ((size_t)b * NT + tc) * (2 * D) + d0;
        const float4 ps = *(const float4*)p;
        const float4 py = *(const float4*)(p + D);
        s.x += ps.x; s.y += ps.y; s.z += ps.z; s.w += ps.w;
        yh.x += py.x; yh.y += py.y; yh.z += py.z; yh.w += py.w;
    }

    float a = fabsf(s.x) + fabsf(s.y) + fabsf(s.z) + fabsf(s.w);
    for (int off = 32; off > 0; off >>= 1)
        a += __shfl_down(a, off, 64);

    __shared__ float psum[4];
    const int wave = tid >> 6;
    const int lane = tid & 63;
    if (lane == 0) psum[wave] = a;
    __syncthreads();
    const float tot = psum[0] + psum[1] + psum[2] + psum[3];
    const float inv = 1.0f / sqrtf(tot);

    float4 y;
    y.x = s.x * inv; y.y = s.y * inv; y.z = s.z * inv; y.w = s.w * inv;
    *(float4*)(out + (size_t)b * D + d0)       = y;   // y
    *(float4*)(out + (size_t)(B + b) * D + d0) = yh;  // y_hat
}

extern "C" void kernel_launch(void* const* d_in, const int* in_sizes, int n_in,
                              void* d_out, int out_size, void* d_ws, size_t ws_size,
                              hipStream_t stream) {
    const float* vs    = (const float*)d_in[0];   // [B,T,D] fp32
    const int*   slen  = (const int*)  d_in[1];   // [B]
    const int*   words = (const int*)  d_in[2];   // [B,T]
    const float* wts   = (const float*)d_in[3];   // [VOCAB]
    float* out  = (float*)d_out;                  // [2*B*D] fp32
    float* part = (float*)d_ws;                   // [B][NT][2*D] = 8 MB

    k1_partial <<<B * NT, 256, 0, stream>>>(vs, slen, words, wts, part);
    k2_finalize<<<B,      256, 0, stream>>>(part, slen, out);
}